// Round 11
// baseline (166.097 us; speedup 1.0000x reference)
//
#include <hip/hip_runtime.h>
#include <math.h>

#define NUM_Q_ 10000
#define NUM_A_ 10000
#define DIM 128
#define MSZ 50
#define BB 64
#define NN 200
#define SEG 8
#define SLEN 25
#define RPOS 8

typedef float f4 __attribute__((ext_vector_type(4)));

__device__ __forceinline__ float hadd(f4 v) { return (v.x + v.y) + (v.z + v.w); }
// m -> slot in [25][56] padded w layout (halves at 0 and 28; 25 used + 3 zero pad)
__device__ __forceinline__ int wslot(int m) { return m + (m >= 25 ? 3 : 0); }

// ============ kernA (proven): gather + GEMVs + softmax -> w/e/ad ============
// grid 512: bid = seg*64 + b (b -> XCD affinity). 256 threads (4 waves).
__global__ __launch_bounds__(256) void kernA(
    const int* __restrict__ q, const int* __restrict__ r, const int* __restrict__ a,
    const float* __restrict__ Kemb, const float* __restrict__ Vemb, const float* __restrict__ VAemb,
    const float* __restrict__ Mk, const float* __restrict__ eW, const float* __restrict__ eb,
    const float* __restrict__ aW, const float* __restrict__ ab,
    float* __restrict__ w_ws, float* __restrict__ e_ws, float* __restrict__ ad_ws)
{
    __shared__ float s_s[SLEN * DIM];
    __shared__ float s_k[SLEN * DIM];
    __shared__ float w_s[SLEN * 56];
    __shared__ int   idxs[96];

    const int bid = blockIdx.x;
    const int b = bid & 63, seg = bid >> 6;
    const int t0 = seg * SLEN;
    const int tid = threadIdx.x;
    const int lane = tid & 63, wv = tid >> 6;

    if (tid < SLEN) {
        int pos = b * NN + t0 + tid;
        int qi = q[pos], ri = r[pos], ai = a[pos];
        idxs[tid]      = qi;
        idxs[32 + tid] = qi + NUM_Q_ * ri;
        idxs[64 + tid] = ai + NUM_A_ * ri;
    }
    for (int k = tid; k < SLEN * 56; k += 256) w_s[k] = 0.f;
    __syncthreads();

    for (int k = tid; k < SLEN * DIM; k += 256) {
        int pl = k >> 7, dc = k & 127;
        s_k[k] = Kemb[(size_t)idxs[pl] * DIM + dc];
        s_s[k] = Vemb[(size_t)idxs[32 + pl] * DIM + dc]
               + VAemb[(size_t)idxs[64 + pl] * DIM + dc];
    }
    __syncthreads();

    {
        const int pw0 = (wv == 0) ? 0 : 7 + 6 * (wv - 1);   // 0,7,13,19
        const int npw = (wv == 0) ? 7 : 6;
        f4 ac0[7], ac1[7], ac2[7], ac3[7], acl[7];
        #pragma unroll
        for (int p = 0; p < 7; ++p) {
            ac0[p] = f4{0,0,0,0}; ac1[p] = f4{0,0,0,0}; ac2[p] = f4{0,0,0,0};
            ac3[p] = f4{0,0,0,0}; acl[p] = f4{0,0,0,0};
        }
        const f4* W0 = (const f4*)(eW + (size_t)lane * DIM);
        const f4* W1 = (const f4*)(eW + (size_t)(lane + 64) * DIM);
        const f4* W2 = (const f4*)(aW + (size_t)lane * DIM);
        const f4* W3 = (const f4*)(aW + (size_t)(lane + 64) * DIM);
        const f4* WM = (const f4*)(Mk + (size_t)(lane < MSZ ? lane : 0) * DIM);

        for (int i4 = 0; i4 < 32; ++i4) {
            f4 w0 = W0[i4], w1 = W1[i4], w2 = W2[i4], w3 = W3[i4], wm = WM[i4];
            #pragma unroll
            for (int p = 0; p < 7; ++p) {
                if (p < npw) {
                    int pos = pw0 + p;
                    f4 s4 = *(const f4*)&s_s[pos * DIM + i4 * 4];
                    f4 k4 = *(const f4*)&s_k[pos * DIM + i4 * 4];
                    ac0[p] += w0 * s4;
                    ac1[p] += w1 * s4;
                    ac2[p] += w2 * s4;
                    ac3[p] += w3 * s4;
                    acl[p] += wm * k4;
                }
            }
        }
        const float eb0 = eb[lane], eb1 = eb[lane + 64];
        const float ab0 = ab[lane], ab1 = ab[lane + 64];
        #pragma unroll
        for (int p = 0; p < 7; ++p) {
            if (p < npw) {
                int pos = pw0 + p;
                size_t g = (size_t)(b * NN + t0 + pos) * DIM;
                e_ws[g + lane]      = 1.f / (1.f + __expf(-(hadd(ac0[p]) + eb0)));
                e_ws[g + lane + 64] = 1.f / (1.f + __expf(-(hadd(ac1[p]) + eb1)));
                ad_ws[g + lane]      = tanhf(hadd(ac2[p]) + ab0);
                ad_ws[g + lane + 64] = tanhf(hadd(ac3[p]) + ab1);
                if (lane < MSZ) w_s[pos * 56 + wslot(lane)] = hadd(acl[p]);
            }
        }
    }
    __syncthreads();

    if (tid < SLEN) {   // softmax over m
        float mx = -1e30f;
        #pragma unroll
        for (int m = 0; m < MSZ; ++m) mx = fmaxf(mx, w_s[tid * 56 + wslot(m)]);
        float sm = 0.f;
        float ex[MSZ];
        #pragma unroll
        for (int m = 0; m < MSZ; ++m) {
            ex[m] = __expf(w_s[tid * 56 + wslot(m)] - mx);
            sm += ex[m];
        }
        float inv = 1.f / sm;
        size_t g = (size_t)(b * NN + t0 + tid) * MSZ;
        #pragma unroll
        for (int m = 0; m < MSZ; ++m)
            w_ws[g + m] = ex[m] * inv;
    }
}

// ============ kernScan v2: unsegmented scan, ZERO in-loop barriers ============
// 256 blocks (bid = dq*64 + b), 256 thr. Thread (mg = tid>>5, d = tid&31) owns
// m = mg+8j at column dq*32+d. rp via wave shuffle + LDS atomicAdd — waves fully
// decoupled; nontemporal Mv stores throttle only on BW.
__global__ __launch_bounds__(256, 1) void kernScan(
    const float* __restrict__ Mv0,
    const float* __restrict__ w_ws, const float* __restrict__ e_ws, const float* __restrict__ ad_ws,
    float* __restrict__ rp, float* __restrict__ Mv)
{
    __shared__ float w_s[NN * MSZ];     // 40 KB
    __shared__ float e_s[NN * 32];      // 25.6 KB
    __shared__ float a_s[NN * 32];      // 25.6 KB
    __shared__ float rp_acc[NN * 32];   // 25.6 KB (116.8 KB total, 1 block/CU)

    const int bid = blockIdx.x;         // bid = dq*64 + b -> xcd = b%8 (same as kernA/C)
    const int b = bid & 63, dq = bid >> 6;
    const int tid = threadIdx.x;
    const int lane = tid & 63;
    const int mg = tid >> 5, d = tid & 31;
    const int NST = (mg < 2) ? 7 : 6;   // wave-uniform per 32-lane half
    const int dg = dq * 32 + d;

    // f4-vectorized staging
    const f4* wb4 = (const f4*)(w_ws + (size_t)b * NN * MSZ);
    for (int k = tid; k < NN * MSZ / 4; k += 256) ((f4*)w_s)[k] = wb4[k];
    for (int k = tid; k < NN * 8; k += 256) {           // 8 f4 per 32-col row
        int t = k >> 3, c4 = k & 7;
        size_t g4 = ((size_t)(b * NN + t) * DIM + dq * 32) / 4 + c4;
        ((f4*)e_s)[k] = ((const f4*)e_ws)[g4];
        ((f4*)a_s)[k] = ((const f4*)ad_ws)[g4];
    }
    for (int k = tid; k < NN * 32; k += 256) rp_acc[k] = 0.f;
    __syncthreads();

    float M[7];
    #pragma unroll
    for (int j = 0; j < 7; ++j)
        M[j] = (j < NST) ? Mv0[(mg + 8 * j) * DIM + dg] : 0.f;

    float* MvB = Mv + (size_t)b * (NN + 1) * MSZ * DIM;
    #pragma unroll
    for (int j = 0; j < 7; ++j)
        if (j < NST) __builtin_nontemporal_store(M[j], &MvB[(mg + 8 * j) * DIM + dg]);

    float* outT = MvB + MSZ * DIM;

    for (int t = 0; t < NN; ++t) {
        float ev = e_s[t * 32 + d], av = a_s[t * 32 + d];
        const float* wrow = w_s + t * MSZ;
        float* o = outT + (size_t)t * MSZ * DIM;
        float pr = 0.f;
        #pragma unroll
        for (int j = 0; j < 7; ++j) {
            if (j < NST) {
                float wj = wrow[mg + 8 * j];                   // LDS broadcast per 32-group
                pr = fmaf(wj, M[j], pr);                       // read pre-update memory
                M[j] = fmaf(wj, fmaf(-M[j], ev, av), M[j]);    // M + w*(a - M*e)
                __builtin_nontemporal_store(M[j], &o[(mg + 8 * j) * DIM + dg]);
            }
        }
        pr += __shfl_xor(pr, 32, 64);                          // sum wave's two mg groups
        if (lane < 32) atomicAdd(&rp_acc[t * 32 + lane], pr);  // ds_add_f32, no barrier
    }
    __syncthreads();

    float* rpo = rp + (size_t)b * NN * DIM + dq * 32;
    for (int k = tid; k < NN * 32; k += 256) {
        int t = k >> 5, c = k & 31;
        __builtin_nontemporal_store(rp_acc[k], &rpo[(size_t)t * DIM + c]);
    }
}

// ============ kernC (proven): f = tanh([reads,k]@fW^T+fb), p = sigmoid(f@pW+pb) ============
__global__ __launch_bounds__(128) void kernC(
    const int* __restrict__ q, const float* __restrict__ Kemb,
    const float* __restrict__ rp,
    const float* __restrict__ fW, const float* __restrict__ fb,
    const float* __restrict__ pW, const float* __restrict__ pb,
    float* __restrict__ p_out)
{
    const int bid = blockIdx.x;
    const int b = bid & 63, grp = bid >> 6;
    const int tid = threadIdx.x;
    const int pos0 = b * NN + grp * RPOS;
    __shared__ float s_cat[RPOS][2 * DIM];
    __shared__ float part[2][RPOS];

    #pragma unroll
    for (int p = 0; p < RPOS; ++p) {
        int pos = pos0 + p;
        s_cat[p][tid] = rp[(size_t)pos * DIM + tid];
        s_cat[p][DIM + tid] = Kemb[(size_t)q[pos] * DIM + tid];
    }
    __syncthreads();

    const f4* fWr = (const f4*)(fW + (size_t)tid * 2 * DIM);
    f4 acc4[RPOS];
    #pragma unroll
    for (int p = 0; p < RPOS; ++p) acc4[p] = f4{0,0,0,0};

    for (int i4 = 0; i4 < (2 * DIM) / 4; ++i4) {
        f4 wf = fWr[i4];
        #pragma unroll
        for (int p = 0; p < RPOS; ++p)
            acc4[p] += ((const f4*)s_cat[p])[i4] * wf;
    }

    float fbv = fb[tid], pwv = pW[tid];
    const int wv = tid >> 6, ln = tid & 63;
    #pragma unroll
    for (int p = 0; p < RPOS; ++p) {
        float v = tanhf(hadd(acc4[p]) + fbv) * pwv;
        #pragma unroll
        for (int off = 32; off >= 1; off >>= 1)
            v += __shfl_xor(v, off, 64);
        if (ln == 0) part[wv][p] = v;
    }
    __syncthreads();
    if (tid < RPOS) {
        float pv = part[0][tid] + part[1][tid] + pb[0];
        p_out[pos0 + tid] = 1.f / (1.f + __expf(-pv));
    }
}

extern "C" void kernel_launch(void* const* d_in, const int* in_sizes, int n_in,
                              void* d_out, int out_size, void* d_ws, size_t ws_size,
                              hipStream_t stream) {
    const int*   q     = (const int*)d_in[0];
    const int*   r     = (const int*)d_in[1];
    const int*   a     = (const int*)d_in[2];
    const float* Kemb  = (const float*)d_in[3];
    const float* Vemb  = (const float*)d_in[4];
    const float* VAemb = (const float*)d_in[5];
    const float* Mk    = (const float*)d_in[6];
    const float* Mv0   = (const float*)d_in[7];
    const float* fW    = (const float*)d_in[8];
    const float* fb    = (const float*)d_in[9];
    const float* pW    = (const float*)d_in[10];
    const float* pb    = (const float*)d_in[11];
    const float* eW    = (const float*)d_in[12];
    const float* eb    = (const float*)d_in[13];
    const float* aW    = (const float*)d_in[14];
    const float* ab    = (const float*)d_in[15];

    float* p_out = (float*)d_out;
    float* Mv    = p_out + BB * NN;

    float* ws    = (float*)d_ws;
    float* w_ws  = ws;                                  // B*N*50
    float* e_ws  = w_ws + (size_t)BB * NN * MSZ;        // B*N*128
    float* ad_ws = e_ws + (size_t)BB * NN * DIM;        // B*N*128
    float* rp    = ad_ws + (size_t)BB * NN * DIM;       // B*N*128

    kernA<<<BB * SEG, 256, 0, stream>>>(q, r, a, Kemb, Vemb, VAemb, Mk,
                                        eW, eb, aW, ab, w_ws, e_ws, ad_ws);
    kernScan<<<BB * 4, 256, 0, stream>>>(Mv0, w_ws, e_ws, ad_ws, rp, Mv);
    kernC<<<BB * NN / RPOS, 128, 0, stream>>>(q, Kemb, rp, fW, fb, pW, pb, p_out);
}

// Round 12
// 159.774 us; speedup vs baseline: 1.0396x; 1.0396x over previous
//
#include <hip/hip_runtime.h>
#include <math.h>

#define NUM_Q_ 10000
#define NUM_A_ 10000
#define DIM 128
#define MSZ 50
#define BB 64
#define NN 200
#define SEG 8
#define SLEN 25
#define RPOS 8
#define TCH 100

typedef float f4 __attribute__((ext_vector_type(4)));

__device__ __forceinline__ float hadd(f4 v) { return (v.x + v.y) + (v.z + v.w); }
// m -> slot in [25][56] padded w layout (halves at 0 and 28; 25 used + 3 zero pad)
__device__ __forceinline__ int wslot(int m) { return m + (m >= 25 ? 3 : 0); }

// ============ kernA (proven): gather + GEMVs + softmax -> w/e/ad ============
// grid 512: bid = seg*64 + b (b -> XCD affinity). 256 threads (4 waves).
__global__ __launch_bounds__(256) void kernA(
    const int* __restrict__ q, const int* __restrict__ r, const int* __restrict__ a,
    const float* __restrict__ Kemb, const float* __restrict__ Vemb, const float* __restrict__ VAemb,
    const float* __restrict__ Mk, const float* __restrict__ eW, const float* __restrict__ eb,
    const float* __restrict__ aW, const float* __restrict__ ab,
    float* __restrict__ w_ws, float* __restrict__ e_ws, float* __restrict__ ad_ws)
{
    __shared__ float s_s[SLEN * DIM];
    __shared__ float s_k[SLEN * DIM];
    __shared__ float w_s[SLEN * 56];
    __shared__ int   idxs[96];

    const int bid = blockIdx.x;
    const int b = bid & 63, seg = bid >> 6;
    const int t0 = seg * SLEN;
    const int tid = threadIdx.x;
    const int lane = tid & 63, wv = tid >> 6;

    if (tid < SLEN) {
        int pos = b * NN + t0 + tid;
        int qi = q[pos], ri = r[pos], ai = a[pos];
        idxs[tid]      = qi;
        idxs[32 + tid] = qi + NUM_Q_ * ri;
        idxs[64 + tid] = ai + NUM_A_ * ri;
    }
    for (int k = tid; k < SLEN * 56; k += 256) w_s[k] = 0.f;
    __syncthreads();

    for (int k = tid; k < SLEN * DIM; k += 256) {
        int pl = k >> 7, dc = k & 127;
        s_k[k] = Kemb[(size_t)idxs[pl] * DIM + dc];
        s_s[k] = Vemb[(size_t)idxs[32 + pl] * DIM + dc]
               + VAemb[(size_t)idxs[64 + pl] * DIM + dc];
    }
    __syncthreads();

    {
        const int pw0 = (wv == 0) ? 0 : 7 + 6 * (wv - 1);   // 0,7,13,19
        const int npw = (wv == 0) ? 7 : 6;
        f4 ac0[7], ac1[7], ac2[7], ac3[7], acl[7];
        #pragma unroll
        for (int p = 0; p < 7; ++p) {
            ac0[p] = f4{0,0,0,0}; ac1[p] = f4{0,0,0,0}; ac2[p] = f4{0,0,0,0};
            ac3[p] = f4{0,0,0,0}; acl[p] = f4{0,0,0,0};
        }
        const f4* W0 = (const f4*)(eW + (size_t)lane * DIM);
        const f4* W1 = (const f4*)(eW + (size_t)(lane + 64) * DIM);
        const f4* W2 = (const f4*)(aW + (size_t)lane * DIM);
        const f4* W3 = (const f4*)(aW + (size_t)(lane + 64) * DIM);
        const f4* WM = (const f4*)(Mk + (size_t)(lane < MSZ ? lane : 0) * DIM);

        for (int i4 = 0; i4 < 32; ++i4) {
            f4 w0 = W0[i4], w1 = W1[i4], w2 = W2[i4], w3 = W3[i4], wm = WM[i4];
            #pragma unroll
            for (int p = 0; p < 7; ++p) {
                if (p < npw) {
                    int pos = pw0 + p;
                    f4 s4 = *(const f4*)&s_s[pos * DIM + i4 * 4];
                    f4 k4 = *(const f4*)&s_k[pos * DIM + i4 * 4];
                    ac0[p] += w0 * s4;
                    ac1[p] += w1 * s4;
                    ac2[p] += w2 * s4;
                    ac3[p] += w3 * s4;
                    acl[p] += wm * k4;
                }
            }
        }
        const float eb0 = eb[lane], eb1 = eb[lane + 64];
        const float ab0 = ab[lane], ab1 = ab[lane + 64];
        #pragma unroll
        for (int p = 0; p < 7; ++p) {
            if (p < npw) {
                int pos = pw0 + p;
                size_t g = (size_t)(b * NN + t0 + pos) * DIM;
                e_ws[g + lane]      = 1.f / (1.f + __expf(-(hadd(ac0[p]) + eb0)));
                e_ws[g + lane + 64] = 1.f / (1.f + __expf(-(hadd(ac1[p]) + eb1)));
                ad_ws[g + lane]      = tanhf(hadd(ac2[p]) + ab0);
                ad_ws[g + lane + 64] = tanhf(hadd(ac3[p]) + ab1);
                if (lane < MSZ) w_s[pos * 56 + wslot(lane)] = hadd(acl[p]);
            }
        }
    }
    __syncthreads();

    if (tid < SLEN) {   // softmax over m
        float mx = -1e30f;
        #pragma unroll
        for (int m = 0; m < MSZ; ++m) mx = fmaxf(mx, w_s[tid * 56 + wslot(m)]);
        float sm = 0.f;
        float ex[MSZ];
        #pragma unroll
        for (int m = 0; m < MSZ; ++m) {
            ex[m] = __expf(w_s[tid * 56 + wslot(m)] - mx);
            sm += ex[m];
        }
        float inv = 1.f / sm;
        size_t g = (size_t)(b * NN + t0 + tid) * MSZ;
        #pragma unroll
        for (int m = 0; m < MSZ; ++m)
            w_ws[g + m] = ex[m] * inv;
    }
}

// ============ kernScan v3: time-chunked, zero per-step sync of any kind ============
// 256 blocks (bid = dq*64 + b), 256 thr, 8 mg x 32 d. Per-wave rp partials go to
// private LDS regions; 4-way combine once per 100-step chunk (6 barriers total).
__global__ __launch_bounds__(256, 1) void kernScan(
    const float* __restrict__ Mv0,
    const float* __restrict__ w_ws, const float* __restrict__ e_ws, const float* __restrict__ ad_ws,
    float* __restrict__ rp, float* __restrict__ Mv)
{
    __shared__ float w_s[TCH * MSZ];      // 20 KB
    __shared__ float e_s[TCH * 32];       // 12.8 KB
    __shared__ float a_s[TCH * 32];       // 12.8 KB
    __shared__ float rp_w[4][TCH * 32];   // 51.2 KB  (94.5 KB total -> 1 block/CU)

    const int bid = blockIdx.x;           // bid = dq*64 + b -> xcd = b%8 (same as kernA/C)
    const int b = bid & 63, dq = bid >> 6;
    const int tid = threadIdx.x;
    const int lane = tid & 63, wv = tid >> 6;
    const int mg = tid >> 5, d = tid & 31;
    const int NST = (mg < 2) ? 7 : 6;     // wave-uniform
    const int dg = dq * 32 + d;

    float M[7];
    #pragma unroll
    for (int j = 0; j < 7; ++j)
        M[j] = (j < NST) ? Mv0[(mg + 8 * j) * DIM + dg] : 0.f;

    float* MvB = Mv + (size_t)b * (NN + 1) * MSZ * DIM;
    #pragma unroll
    for (int j = 0; j < 7; ++j)
        if (j < NST) __builtin_nontemporal_store(M[j], &MvB[(mg + 8 * j) * DIM + dg]);
    float* outT = MvB + MSZ * DIM;

    for (int c0 = 0; c0 < NN; c0 += TCH) {
        __syncthreads();                  // rp_w/LDS of previous chunk fully consumed
        // f4-vectorized chunk staging
        const f4* wb4 = (const f4*)(w_ws + ((size_t)b * NN + c0) * MSZ);
        for (int k = tid; k < TCH * MSZ / 4; k += 256) ((f4*)w_s)[k] = wb4[k];
        for (int k = tid; k < TCH * 8; k += 256) {       // 8 f4 per 32-col row
            int t = k >> 3, c4 = k & 7;
            size_t g4 = ((size_t)(b * NN + c0 + t) * DIM + dq * 32) / 4 + c4;
            ((f4*)e_s)[k] = ((const f4*)e_ws)[g4];
            ((f4*)a_s)[k] = ((const f4*)ad_ws)[g4];
        }
        __syncthreads();

        for (int tl = 0; tl < TCH; ++tl) {
            float ev = e_s[tl * 32 + d], av = a_s[tl * 32 + d];
            const float* wrow = w_s + tl * MSZ;
            float* o = outT + (size_t)(c0 + tl) * MSZ * DIM;
            float pr = 0.f;
            #pragma unroll
            for (int j = 0; j < 7; ++j) {
                if (j < NST) {
                    float wj = wrow[mg + 8 * j];                 // LDS broadcast
                    pr = fmaf(wj, M[j], pr);                     // read pre-update memory
                    M[j] = fmaf(wj, fmaf(-M[j], ev, av), M[j]);  // M + w*(a - M*e)
                    __builtin_nontemporal_store(M[j], &o[(mg + 8 * j) * DIM + dg]);
                }
            }
            pr += __shfl_xor(pr, 32, 64);                        // mg-pair sum within wave
            if (lane < 32) rp_w[wv][tl * 32 + lane] = pr;        // private region, no sync
        }
        __syncthreads();

        // chunk rp combine + writeout (cached stores; kernC reads it next)
        float* rpo = rp + ((size_t)b * NN + c0) * DIM + dq * 32;
        for (int k = tid; k < TCH * 32; k += 256) {
            int tl = k >> 5, c = k & 31;
            float s = (rp_w[0][k] + rp_w[1][k]) + (rp_w[2][k] + rp_w[3][k]);
            rpo[(size_t)tl * DIM + c] = s;
        }
    }
}

// ============ kernC (proven): f = tanh([reads,k]@fW^T+fb), p = sigmoid(f@pW+pb) ============
__global__ __launch_bounds__(128) void kernC(
    const int* __restrict__ q, const float* __restrict__ Kemb,
    const float* __restrict__ rp,
    const float* __restrict__ fW, const float* __restrict__ fb,
    const float* __restrict__ pW, const float* __restrict__ pb,
    float* __restrict__ p_out)
{
    const int bid = blockIdx.x;
    const int b = bid & 63, grp = bid >> 6;
    const int tid = threadIdx.x;
    const int pos0 = b * NN + grp * RPOS;
    __shared__ float s_cat[RPOS][2 * DIM];
    __shared__ float part[2][RPOS];

    #pragma unroll
    for (int p = 0; p < RPOS; ++p) {
        int pos = pos0 + p;
        s_cat[p][tid] = rp[(size_t)pos * DIM + tid];
        s_cat[p][DIM + tid] = Kemb[(size_t)q[pos] * DIM + tid];
    }
    __syncthreads();

    const f4* fWr = (const f4*)(fW + (size_t)tid * 2 * DIM);
    f4 acc4[RPOS];
    #pragma unroll
    for (int p = 0; p < RPOS; ++p) acc4[p] = f4{0,0,0,0};

    for (int i4 = 0; i4 < (2 * DIM) / 4; ++i4) {
        f4 wf = fWr[i4];
        #pragma unroll
        for (int p = 0; p < RPOS; ++p)
            acc4[p] += ((const f4*)s_cat[p])[i4] * wf;
    }

    float fbv = fb[tid], pwv = pW[tid];
    const int wv = tid >> 6, ln = tid & 63;
    #pragma unroll
    for (int p = 0; p < RPOS; ++p) {
        float v = tanhf(hadd(acc4[p]) + fbv) * pwv;
        #pragma unroll
        for (int off = 32; off >= 1; off >>= 1)
            v += __shfl_xor(v, off, 64);
        if (ln == 0) part[wv][p] = v;
    }
    __syncthreads();
    if (tid < RPOS) {
        float pv = part[0][tid] + part[1][tid] + pb[0];
        p_out[pos0 + tid] = 1.f / (1.f + __expf(-pv));
    }
}

extern "C" void kernel_launch(void* const* d_in, const int* in_sizes, int n_in,
                              void* d_out, int out_size, void* d_ws, size_t ws_size,
                              hipStream_t stream) {
    const int*   q     = (const int*)d_in[0];
    const int*   r     = (const int*)d_in[1];
    const int*   a     = (const int*)d_in[2];
    const float* Kemb  = (const float*)d_in[3];
    const float* Vemb  = (const float*)d_in[4];
    const float* VAemb = (const float*)d_in[5];
    const float* Mk    = (const float*)d_in[6];
    const float* Mv0   = (const float*)d_in[7];
    const float* fW    = (const float*)d_in[8];
    const float* fb    = (const float*)d_in[9];
    const float* pW    = (const float*)d_in[10];
    const float* pb    = (const float*)d_in[11];
    const float* eW    = (const float*)d_in[12];
    const float* eb    = (const float*)d_in[13];
    const float* aW    = (const float*)d_in[14];
    const float* ab    = (const float*)d_in[15];

    float* p_out = (float*)d_out;
    float* Mv    = p_out + BB * NN;

    float* ws    = (float*)d_ws;
    float* w_ws  = ws;                                  // B*N*50
    float* e_ws  = w_ws + (size_t)BB * NN * MSZ;        // B*N*128
    float* ad_ws = e_ws + (size_t)BB * NN * DIM;        // B*N*128
    float* rp    = ad_ws + (size_t)BB * NN * DIM;       // B*N*128

    kernA<<<BB * SEG, 256, 0, stream>>>(q, r, a, Kemb, Vemb, VAemb, Mk,
                                        eW, eb, aW, ab, w_ws, e_ws, ad_ws);
    kernScan<<<BB * 4, 256, 0, stream>>>(Mv0, w_ws, e_ws, ad_ws, rp, Mv);
    kernC<<<BB * NN / RPOS, 128, 0, stream>>>(q, Kemb, rp, fW, fb, pW, pb, p_out);
}

// Round 13
// 143.300 us; speedup vs baseline: 1.1591x; 1.1150x over previous
//
#include <hip/hip_runtime.h>
#include <math.h>

#define NUM_Q_ 10000
#define NUM_A_ 10000
#define DIM 128
#define MSZ 50
#define BB 64
#define NN 200
#define SEG 8
#define SLEN 25
#define TCH 100

typedef float f4 __attribute__((ext_vector_type(4)));
typedef short bf16x8 __attribute__((ext_vector_type(8)));
typedef float f32x4 __attribute__((ext_vector_type(4)));

__device__ __forceinline__ float hadd(f4 v) { return (v.x + v.y) + (v.z + v.w); }
// m -> slot in [25][56] padded w layout (halves at 0 and 28; 25 used + 3 zero pad)
__device__ __forceinline__ int wslot(int m) { return m + (m >= 25 ? 3 : 0); }
__device__ __forceinline__ ushort f2bf(float v) {   // RNE f32 -> bf16
    union { float f; unsigned u; } c; c.f = v;
    return (ushort)((c.u + 0x7fff + ((c.u >> 16) & 1)) >> 16);
}

// ============ kernA: gather + GEMVs + softmax -> w/e/ad  (+ fW->bf16 frag copy) ============
// grid 512: bid = seg*64 + b (b -> XCD affinity). 256 threads (4 waves).
__global__ __launch_bounds__(256) void kernA(
    const int* __restrict__ q, const int* __restrict__ r, const int* __restrict__ a,
    const float* __restrict__ Kemb, const float* __restrict__ Vemb, const float* __restrict__ VAemb,
    const float* __restrict__ Mk, const float* __restrict__ eW, const float* __restrict__ eb,
    const float* __restrict__ aW, const float* __restrict__ ab,
    const float* __restrict__ fW, ushort* __restrict__ fWfrag,
    float* __restrict__ w_ws, float* __restrict__ e_ws, float* __restrict__ ad_ws)
{
    __shared__ float s_s[SLEN * DIM];
    __shared__ float s_k[SLEN * DIM];
    __shared__ float w_s[SLEN * 56];
    __shared__ int   idxs[96];

    const int bid = blockIdx.x;
    const int b = bid & 63, seg = bid >> 6;
    const int t0 = seg * SLEN;
    const int tid = threadIdx.x;
    const int lane = tid & 63, wv = tid >> 6;

    // seg==0 blocks also emit fW in bf16 MFMA-fragment order (for kernC):
    // fWfrag[((ntile*8 + kstep)*64 + lane)*8 + j] = bf16(fW[ntile*16 + (lane&15)][kstep*32 + (lane>>4)*8 + j])
    if (seg == 0) {
        int n = b & 7, s = (b >> 3) & 7;
        int l = tid >> 2, jj = tid & 3;
        int row = n * 16 + (l & 15);
        int k = s * 32 + (l >> 4) * 8 + jj * 2;
        ushort v0 = f2bf(fW[row * 256 + k]);
        ushort v1 = f2bf(fW[row * 256 + k + 1]);
        ushort* dst = fWfrag + (size_t)((n * 8 + s) * 64 + l) * 8 + jj * 2;
        dst[0] = v0; dst[1] = v1;
    }

    if (tid < SLEN) {
        int pos = b * NN + t0 + tid;
        int qi = q[pos], ri = r[pos], ai = a[pos];
        idxs[tid]      = qi;
        idxs[32 + tid] = qi + NUM_Q_ * ri;
        idxs[64 + tid] = ai + NUM_A_ * ri;
    }
    for (int k = tid; k < SLEN * 56; k += 256) w_s[k] = 0.f;
    __syncthreads();

    for (int k = tid; k < SLEN * DIM; k += 256) {
        int pl = k >> 7, dc = k & 127;
        s_k[k] = Kemb[(size_t)idxs[pl] * DIM + dc];
        s_s[k] = Vemb[(size_t)idxs[32 + pl] * DIM + dc]
               + VAemb[(size_t)idxs[64 + pl] * DIM + dc];
    }
    __syncthreads();

    {
        const int pw0 = (wv == 0) ? 0 : 7 + 6 * (wv - 1);   // 0,7,13,19
        const int npw = (wv == 0) ? 7 : 6;
        f4 ac0[7], ac1[7], ac2[7], ac3[7], acl[7];
        #pragma unroll
        for (int p = 0; p < 7; ++p) {
            ac0[p] = f4{0,0,0,0}; ac1[p] = f4{0,0,0,0}; ac2[p] = f4{0,0,0,0};
            ac3[p] = f4{0,0,0,0}; acl[p] = f4{0,0,0,0};
        }
        const f4* W0 = (const f4*)(eW + (size_t)lane * DIM);
        const f4* W1 = (const f4*)(eW + (size_t)(lane + 64) * DIM);
        const f4* W2 = (const f4*)(aW + (size_t)lane * DIM);
        const f4* W3 = (const f4*)(aW + (size_t)(lane + 64) * DIM);
        const f4* WM = (const f4*)(Mk + (size_t)(lane < MSZ ? lane : 0) * DIM);

        for (int i4 = 0; i4 < 32; ++i4) {
            f4 w0 = W0[i4], w1 = W1[i4], w2 = W2[i4], w3 = W3[i4], wm = WM[i4];
            #pragma unroll
            for (int p = 0; p < 7; ++p) {
                if (p < npw) {
                    int pos = pw0 + p;
                    f4 s4 = *(const f4*)&s_s[pos * DIM + i4 * 4];
                    f4 k4 = *(const f4*)&s_k[pos * DIM + i4 * 4];
                    ac0[p] += w0 * s4;
                    ac1[p] += w1 * s4;
                    ac2[p] += w2 * s4;
                    ac3[p] += w3 * s4;
                    acl[p] += wm * k4;
                }
            }
        }
        const float eb0 = eb[lane], eb1 = eb[lane + 64];
        const float ab0 = ab[lane], ab1 = ab[lane + 64];
        #pragma unroll
        for (int p = 0; p < 7; ++p) {
            if (p < npw) {
                int pos = pw0 + p;
                size_t g = (size_t)(b * NN + t0 + pos) * DIM;
                e_ws[g + lane]      = 1.f / (1.f + __expf(-(hadd(ac0[p]) + eb0)));
                e_ws[g + lane + 64] = 1.f / (1.f + __expf(-(hadd(ac1[p]) + eb1)));
                ad_ws[g + lane]      = tanhf(hadd(ac2[p]) + ab0);
                ad_ws[g + lane + 64] = tanhf(hadd(ac3[p]) + ab1);
                if (lane < MSZ) w_s[pos * 56 + wslot(lane)] = hadd(acl[p]);
            }
        }
    }
    __syncthreads();

    if (tid < SLEN) {   // softmax over m
        float mx = -1e30f;
        #pragma unroll
        for (int m = 0; m < MSZ; ++m) mx = fmaxf(mx, w_s[tid * 56 + wslot(m)]);
        float sm = 0.f;
        float ex[MSZ];
        #pragma unroll
        for (int m = 0; m < MSZ; ++m) {
            ex[m] = __expf(w_s[tid * 56 + wslot(m)] - mx);
            sm += ex[m];
        }
        float inv = 1.f / sm;
        size_t g = (size_t)(b * NN + t0 + tid) * MSZ;
        #pragma unroll
        for (int m = 0; m < MSZ; ++m)
            w_ws[g + m] = ex[m] * inv;
    }
}

// ============ kernScan (proven R12): time-chunked, no per-step sync ============
__global__ __launch_bounds__(256, 1) void kernScan(
    const float* __restrict__ Mv0,
    const float* __restrict__ w_ws, const float* __restrict__ e_ws, const float* __restrict__ ad_ws,
    float* __restrict__ rp, float* __restrict__ Mv)
{
    __shared__ float w_s[TCH * MSZ];
    __shared__ float e_s[TCH * 32];
    __shared__ float a_s[TCH * 32];
    __shared__ float rp_w[4][TCH * 32];

    const int bid = blockIdx.x;           // bid = dq*64 + b -> xcd = b%8
    const int b = bid & 63, dq = bid >> 6;
    const int tid = threadIdx.x;
    const int lane = tid & 63, wv = tid >> 6;
    const int mg = tid >> 5, d = tid & 31;
    const int NST = (mg < 2) ? 7 : 6;
    const int dg = dq * 32 + d;

    float M[7];
    #pragma unroll
    for (int j = 0; j < 7; ++j)
        M[j] = (j < NST) ? Mv0[(mg + 8 * j) * DIM + dg] : 0.f;

    float* MvB = Mv + (size_t)b * (NN + 1) * MSZ * DIM;
    #pragma unroll
    for (int j = 0; j < 7; ++j)
        if (j < NST) __builtin_nontemporal_store(M[j], &MvB[(mg + 8 * j) * DIM + dg]);
    float* outT = MvB + MSZ * DIM;

    for (int c0 = 0; c0 < NN; c0 += TCH) {
        __syncthreads();
        const f4* wb4 = (const f4*)(w_ws + ((size_t)b * NN + c0) * MSZ);
        for (int k = tid; k < TCH * MSZ / 4; k += 256) ((f4*)w_s)[k] = wb4[k];
        for (int k = tid; k < TCH * 8; k += 256) {
            int t = k >> 3, c4 = k & 7;
            size_t g4 = ((size_t)(b * NN + c0 + t) * DIM + dq * 32) / 4 + c4;
            ((f4*)e_s)[k] = ((const f4*)e_ws)[g4];
            ((f4*)a_s)[k] = ((const f4*)ad_ws)[g4];
        }
        __syncthreads();

        for (int tl = 0; tl < TCH; ++tl) {
            float ev = e_s[tl * 32 + d], av = a_s[tl * 32 + d];
            const float* wrow = w_s + tl * MSZ;
            float* o = outT + (size_t)(c0 + tl) * MSZ * DIM;
            float pr = 0.f;
            #pragma unroll
            for (int j = 0; j < 7; ++j) {
                if (j < NST) {
                    float wj = wrow[mg + 8 * j];
                    pr = fmaf(wj, M[j], pr);
                    M[j] = fmaf(wj, fmaf(-M[j], ev, av), M[j]);
                    __builtin_nontemporal_store(M[j], &o[(mg + 8 * j) * DIM + dg]);
                }
            }
            pr += __shfl_xor(pr, 32, 64);
            if (lane < 32) rp_w[wv][tl * 32 + lane] = pr;
        }
        __syncthreads();

        float* rpo = rp + ((size_t)b * NN + c0) * DIM + dq * 32;
        for (int k = tid; k < TCH * 32; k += 256) {
            int tl = k >> 5, c = k & 31;
            float s = (rp_w[0][k] + rp_w[1][k]) + (rp_w[2][k] + rp_w[3][k]);
            rpo[(size_t)tl * DIM + c] = s;
        }
    }
}

// ============ kernC v2 (MFMA): f = tanh([rp,k]@fW^T+fb), p = sigmoid(f@pW+pb) ============
// grid 832: bid = pg*64 + b; 16 positions/block; 256 thr (4 waves, 2 N-tiles each).
__global__ __launch_bounds__(256) void kernC(
    const int* __restrict__ q, const float* __restrict__ Kemb,
    const float* __restrict__ rp, const ushort* __restrict__ fWfrag,
    const float* __restrict__ fb, const float* __restrict__ pW, const float* __restrict__ pb,
    float* __restrict__ p_out)
{
    __shared__ __align__(16) ushort cat[16 * 264];   // bf16, stride 264 (2-way-free banks)
    __shared__ float part[4][16];

    const int bid = blockIdx.x;
    const int b = bid & 63, pg = bid >> 6;
    const int tid = threadIdx.x;
    const int lane = tid & 63, wv = tid >> 6;
    const int base = b * NN + pg * 16;
    const int nvalid = (NN - pg * 16 < 16) ? (NN - pg * 16) : 16;

    for (int kidx = tid; kidx < 16 * 256; kidx += 256) {
        int row = kidx >> 8, col = kidx & 255;
        int pos = base + (row < nvalid ? row : 0);
        float v = (col < 128) ? rp[(size_t)pos * DIM + col]
                              : Kemb[(size_t)q[pos] * DIM + (col - 128)];
        cat[row * 264 + col] = f2bf(v);
    }
    __syncthreads();

    const int r16 = lane & 15, g = lane >> 4;
    f32x4 acc0 = {0, 0, 0, 0}, acc1 = {0, 0, 0, 0};
    #pragma unroll
    for (int ks = 0; ks < 8; ++ks) {
        bf16x8 av = *(const bf16x8*)&cat[r16 * 264 + ks * 32 + g * 8];
        bf16x8 b0 = *(const bf16x8*)&fWfrag[(size_t)(((wv * 2 + 0) * 8 + ks) * 64 + lane) * 8];
        bf16x8 b1 = *(const bf16x8*)&fWfrag[(size_t)(((wv * 2 + 1) * 8 + ks) * 64 + lane) * 8];
        acc0 = __builtin_amdgcn_mfma_f32_16x16x32_bf16(av, b0, acc0, 0, 0, 0);
        acc1 = __builtin_amdgcn_mfma_f32_16x16x32_bf16(av, b1, acc1, 0, 0, 0);
    }

    // D layout: col = lane&15 (+ntile*16), row(pos) = g*4 + reg
    const int c0 = wv * 32 + r16, c1 = c0 + 16;
    const float fb0 = fb[c0], fb1 = fb[c1];
    const float pw0 = pW[c0], pw1 = pW[c1];
    #pragma unroll
    for (int rg = 0; rg < 4; ++rg) {
        float v = tanhf(acc0[rg] + fb0) * pw0 + tanhf(acc1[rg] + fb1) * pw1;
        v += __shfl_xor(v, 1, 64);
        v += __shfl_xor(v, 2, 64);
        v += __shfl_xor(v, 4, 64);
        v += __shfl_xor(v, 8, 64);
        if (r16 == 0) part[wv][g * 4 + rg] = v;
    }
    __syncthreads();
    if (tid < nvalid) {
        float s = part[0][tid] + part[1][tid] + part[2][tid] + part[3][tid] + pb[0];
        p_out[base + tid] = 1.f / (1.f + __expf(-s));
    }
}

extern "C" void kernel_launch(void* const* d_in, const int* in_sizes, int n_in,
                              void* d_out, int out_size, void* d_ws, size_t ws_size,
                              hipStream_t stream) {
    const int*   q     = (const int*)d_in[0];
    const int*   r     = (const int*)d_in[1];
    const int*   a     = (const int*)d_in[2];
    const float* Kemb  = (const float*)d_in[3];
    const float* Vemb  = (const float*)d_in[4];
    const float* VAemb = (const float*)d_in[5];
    const float* Mk    = (const float*)d_in[6];
    const float* Mv0   = (const float*)d_in[7];
    const float* fW    = (const float*)d_in[8];
    const float* fb    = (const float*)d_in[9];
    const float* pW    = (const float*)d_in[10];
    const float* pb    = (const float*)d_in[11];
    const float* eW    = (const float*)d_in[12];
    const float* eb    = (const float*)d_in[13];
    const float* aW    = (const float*)d_in[14];
    const float* ab    = (const float*)d_in[15];

    float* p_out = (float*)d_out;
    float* Mv    = p_out + BB * NN;

    float* ws     = (float*)d_ws;
    float* w_ws   = ws;                                   // B*N*50
    float* e_ws   = w_ws + (size_t)BB * NN * MSZ;         // B*N*128
    float* ad_ws  = e_ws + (size_t)BB * NN * DIM;         // B*N*128
    float* rp     = ad_ws + (size_t)BB * NN * DIM;        // B*N*128
    ushort* fWfrag = (ushort*)(rp + (size_t)BB * NN * DIM); // 128*256 bf16

    kernA<<<BB * SEG, 256, 0, stream>>>(q, r, a, Kemb, Vemb, VAemb, Mk,
                                        eW, eb, aW, ab, fW, fWfrag,
                                        w_ws, e_ws, ad_ws);
    kernScan<<<BB * 4, 256, 0, stream>>>(Mv0, w_ws, e_ws, ad_ws, rp, Mv);
    kernC<<<BB * 13, 256, 0, stream>>>(q, Kemb, rp, fWfrag, fb, pW, pb, p_out);
}